// Round 12
// baseline (462.220 us; speedup 1.0000x reference)
//
#include <hip/hip_runtime.h>

typedef _Float16 v8h __attribute__((ext_vector_type(8)));
typedef _Float16 v4h __attribute__((ext_vector_type(4)));
typedef float    v4f __attribute__((ext_vector_type(4)));

template<int V> struct IC { static constexpr int value = V; };

__device__ __forceinline__ float fast_tanh(float x) {
    float e = __expf(2.0f * x);
    return 1.0f - 2.0f / (e + 1.0f);
}

// ---------------------------------------------------------------------------
// pack layout (halves):
//  hidden: idx = ((((pipe*3+l)*8 + nt)*4 + kk)*64 + lane)*8 + j     [0, 98304)
//  L0 (legacy, unused):                                             [98304, 106496)
//  wout A-fragments: 106496 + ((pipe*4 + kk)*64 + lane)*8 + j       [106496, 110592)
// ---------------------------------------------------------------------------
__global__ void pack_weights(const float* __restrict__ dpWh,
                             const float* __restrict__ icWh,
                             const float* __restrict__ dpWin,
                             const float* __restrict__ icWin,
                             const float* __restrict__ dpWout,
                             const float* __restrict__ icWout,
                             _Float16* __restrict__ out) {
    int idx = blockIdx.x * 256 + threadIdx.x;
    if (idx < 98304) {
        int j    = idx & 7;
        int lane = (idx >> 3) & 63;
        int kk   = (idx >> 9) & 3;
        int nt   = (idx >> 11) & 7;
        int lp   = idx >> 14;           // 0..5
        int l    = lp % 3;
        const float* src = (lp >= 3) ? icWh : dpWh;
        int k = kk * 32 + (lane >> 4) * 8 + j;
        int n = nt * 16 + (lane & 15);
        out[idx] = (_Float16)src[(l * 128 + k) * 128 + n];
    } else if (idx < 106496) {
        int f    = idx - 98304;
        int j    = f & 7;
        int lane = (f >> 3) & 63;
        int nt   = (f >> 9) & 7;
        int pipe = (f >> 12) & 1;
        int k = (lane >> 4) * 8 + j;
        int n = nt * 16 + (lane & 15);
        float v = 0.0f;
        if (pipe == 0) { if (k < 4) v = dpWin[k * 128 + n]; }
        else           { if (k < 3) v = icWin[k * 128 + n]; }
        out[idx] = (_Float16)v;
    } else if (idx < 110592) {
        int f    = idx - 106496;
        int j    = f & 7;
        int lane = (f >> 3) & 63;
        int kk   = (f >> 9) & 3;
        int pipe = (f >> 11) & 1;
        float v = 0.0f;
        if ((lane & 15) == 0)
            v = (pipe ? icWout : dpWout)[kk * 32 + (lane >> 4) * 8 + j];
        out[idx] = (_Float16)v;
    }
}

// LDS (dynamic, 80896 B -> 2 blocks/CU):
//   [0,     34816)  act0 : 128 vrows x ROWH halves
//   [34816, 69632)  act1
//   [69632, 73728)  btab : f32[8][128]  0=dpBin 1..3=dpBh 4=icBin 5..7=icBh
//   [73728, 77824)  winb : f32[8][128]  0..3=dpWin k, 4..6=icWin k, 7=0
//   [77824, 78848)  cbuf : f32[256]
//   [78848, 80896)  rowb : f32[2][16][16] geometry, ping-pong by batch parity
//     slots: 0=t 1=xr 2=yr 3=zr 4..6=dth 7..8=dph 9=sEnv 10=dsdr 11=Aan 12=dAdr
//            13=r 14=th 15=ph
#define ROWH 136
#define ABUFH (128 * ROWH)
#define SMEM_BYTES 80896

// LB(512,4): 128 unified regs/thread. Persistent weights now 48 (dp only; ic
// streamed from L2 per batch) -> fits the AGPR half; transients fit arch half.
__launch_bounds__(512, 4)
__global__ void node_main(const float* __restrict__ tx,
                          const float* __restrict__ dpBin, const float* __restrict__ dpBh,
                          const float* __restrict__ icBin, const float* __restrict__ icBh,
                          const float* __restrict__ dpWin, const float* __restrict__ icWin,
                          const float* __restrict__ dpBout, const float* __restrict__ icBout,
                          const _Float16* __restrict__ pack,
                          float* __restrict__ outPot, float* __restrict__ outAcc,
                          int N)
{
    extern __shared__ char smem[];
    _Float16* act0 = (_Float16*)smem;
    _Float16* act1 = act0 + ABUFH;
    float* btab = (float*)(smem + 69632);
    float* winb = (float*)(smem + 73728);
    float* cbuf = (float*)(smem + 77824);
    float* rowb = (float*)(smem + 78848);

    const int tid  = threadIdx.x;
    const int wave = tid >> 6;          // 0..7 = my 16-feature slice cs
    const int lane = tid & 63;
    const int l15  = lane & 15;
    const int s    = lane >> 4;
    const int cs   = wave;
    const int fb   = cs * 16 + s * 4;   // my 4 output features

    // ---- stage bias + input-layer weight tables ----
    for (int i = tid; i < 1024; i += 512) {
        int row = i >> 7, col = i & 127;
        float bv, wv;
        if      (row == 0) bv = dpBin[col];
        else if (row <  4) bv = dpBh[(row - 1) * 128 + col];
        else if (row == 4) bv = icBin[col];
        else               bv = icBh[(row - 5) * 128 + col];
        if      (row <  4) wv = dpWin[row * 128 + col];
        else if (row <  7) wv = icWin[(row - 4) * 128 + col];
        else               wv = 0.0f;
        btab[i] = bv;
        winb[i] = wv;
    }

    // ---- persistent weights: dp layers only (48 VGPRs) ----
    v8h wreg[3][4];
    #pragma unroll
    for (int L = 0; L < 3; L++)
        #pragma unroll
        for (int kk = 0; kk < 4; kk++)
            wreg[L][kk] = *(const v8h*)(pack + (((L * 8 + cs) * 4 + kk) << 9) + (lane << 3));

    const float boutd = dpBout[0];
    const float bouti = icBout[0];
    __syncthreads();

    // ---- static LDS bases ----
    _Float16* ep0 = act0 + l15 * ROWH + fb;            // epilogue writes
    _Float16* ep1 = act1 + l15 * ROWH + fb;
    const _Float16* rd0 = act0 + l15 * ROWH + s * 8;   // B-fragment reads
    const _Float16* rd1 = act1 + l15 * ROWH + s * 8;

    auto epi_p = [&](v4f acc, v4f& Dk, _Float16* p) {
        float h0 = fast_tanh(acc[0]), h1 = fast_tanh(acc[1]);
        float h2 = fast_tanh(acc[2]), h3 = fast_tanh(acc[3]);
        Dk[0] = 1.0f - h0 * h0; Dk[1] = 1.0f - h1 * h1;
        Dk[2] = 1.0f - h2 * h2; Dk[3] = 1.0f - h3 * h3;
        v4h w = {(_Float16)h0, (_Float16)h1, (_Float16)h2, (_Float16)h3};
        *(v4h*)p = w;
    };
    auto epi_t = [&](v4f acc, const v4f& Dk, _Float16* p) {
        v4h w = {(_Float16)(Dk[0] * acc[0]), (_Float16)(Dk[1] * acc[1]),
                 (_Float16)(Dk[2] * acc[2]), (_Float16)(Dk[3] * acc[3])};
        *(v4h*)p = w;
    };

    // one hidden layer over a half-batch. IC1: local set 1 is the ic pipe,
    // whose weight slice is loaded transiently (L2-resident) at entry.
    auto hpass = [&](auto Lc, auto G1c, const _Float16* rb, _Float16* wb) {
        constexpr int  L   = decltype(Lc)::value;
        constexpr bool IC1 = (decltype(G1c)::value == 1);
        v8h icw[4];
        if constexpr (IC1) {
            #pragma unroll
            for (int kk = 0; kk < 4; kk++)
                icw[kk] = *(const v8h*)(pack + ((((3 + L) * 8 + cs) * 4 + kk) << 9) + (lane << 3));
        }
        #pragma unroll
        for (int ls = 0; ls < 2; ls++) {
            const bool icp = IC1 && (ls == 1);
            const float* brow = btab + (icp ? (5 + L) : (1 + L)) * 128 + fb;
            v4f Dk;
            #pragma unroll
            for (int st = 0; st < 4; st++) {
                const int ro = (ls * 64 + st * 16) * ROWH;
                v8h b0 = *(const v8h*)(rb + ro);
                v8h b1 = *(const v8h*)(rb + ro + 32);
                v8h b2 = *(const v8h*)(rb + ro + 64);
                v8h b3 = *(const v8h*)(rb + ro + 96);
                v4f acc;
                if (st == 0) acc = *(const v4f*)brow;
                else { v4f z = {0.f, 0.f, 0.f, 0.f}; acc = z; }
                if (icp) {
                    acc = __builtin_amdgcn_mfma_f32_16x16x32_f16(icw[0], b0, acc, 0, 0, 0);
                    acc = __builtin_amdgcn_mfma_f32_16x16x32_f16(icw[1], b1, acc, 0, 0, 0);
                    acc = __builtin_amdgcn_mfma_f32_16x16x32_f16(icw[2], b2, acc, 0, 0, 0);
                    acc = __builtin_amdgcn_mfma_f32_16x16x32_f16(icw[3], b3, acc, 0, 0, 0);
                } else {
                    acc = __builtin_amdgcn_mfma_f32_16x16x32_f16(wreg[L][0], b0, acc, 0, 0, 0);
                    acc = __builtin_amdgcn_mfma_f32_16x16x32_f16(wreg[L][1], b1, acc, 0, 0, 0);
                    acc = __builtin_amdgcn_mfma_f32_16x16x32_f16(wreg[L][2], b2, acc, 0, 0, 0);
                    acc = __builtin_amdgcn_mfma_f32_16x16x32_f16(wreg[L][3], b3, acc, 0, 0, 0);
                }
                _Float16* p = wb + (ls * 64 + st * 16) * ROWH;
                if (st == 0) epi_p(acc, Dk, p);
                else         epi_t(acc, Dk, p);
            }
        }
    };

    const float NP0 = 1.0f - 0.7745966692414834f;   // GL node+1
    const float NP2 = 1.0f + 0.7745966692414834f;

    const int nbat = (N + 15) >> 4;
    int par = 0;
    for (int b = blockIdx.x; b < nbat; b += gridDim.x, par ^= 1) {
        // ---- geometry: wave 0 computes, everyone reads (rowb ping-pong) ----
        if (wave == 0 && lane < 16) {
            int prow = b * 16 + lane;
            float4 q = (prow < N) ? ((const float4*)tx)[prow] : make_float4(0.f, 1.f, 1.f, 1.f);
            float t = q.x, x = q.y, y = q.z, z = q.w;
            float r2 = x * x + y * y + z * z;
            float r  = sqrtf(r2 + 1e-12f);
            float rinv = 1.0f / r;
            float uc = fminf(1.0f, fmaxf(-1.0f, z * rinv));
            float th = acosf(uc);
            float ph = atan2f(y, x);
            float rinv3 = rinv * rinv * rinv;
            float dacos = -1.0f / sqrtf(fmaxf(1.0f - uc * uc, 1e-30f));
            float rho2 = fmaxf(x * x + y * y, 1e-30f);
            float opr  = 1.0f + r;
            float den  = r * r + 0.1f;
            float isq  = 1.0f / sqrtf(den);
            float* rbp = rowb + par * 256 + lane * 16;
            rbp[0]  = t;
            rbp[1]  = x * rinv; rbp[2] = y * rinv; rbp[3] = z * rinv;
            rbp[4]  = dacos * (-x * z * rinv3);
            rbp[5]  = dacos * (-y * z * rinv3);
            rbp[6]  = dacos * (rinv - z * z * rinv3);
            rbp[7]  = -y / rho2;
            rbp[8]  =  x / rho2;
            rbp[9]  = -1.0f / opr;
            rbp[10] =  1.0f / (opr * opr);
            rbp[11] = -isq;
            rbp[12] = r * isq * isq * isq;
            rbp[13] = r; rbp[14] = th; rbp[15] = ph;
        }
        __syncthreads();                               // rowb ready

        const float* rbl = rowb + par * 256 + l15 * 16;
        float t = rbl[0], r = rbl[13], th = rbl[14], ph = rbl[15];

        // ---- two half-batches: global sets {0,1} then {2,3} ----
        #pragma unroll
        for (int g = 0; g < 2; g++) {
            // L0 (pure fp32 VALU): 2 sets -> act0
            #pragma unroll
            for (int ls = 0; ls < 2; ls++) {
                const int set = g * 2 + ls;
                const bool icp = (set == 3);
                const float* wb = winb + (icp ? 512 : 0);
                v4f pre = *(const v4f*)(btab + (icp ? 512 : 0) + fb);
                v4f w0 = *(const v4f*)(wb + fb);
                v4f w1 = *(const v4f*)(wb + 128 + fb);
                v4f w2 = *(const v4f*)(wb + 256 + fb);
                v4f w3;
                if (icp) { v4f z = {0.f, 0.f, 0.f, 0.f}; w3 = z; }
                else     w3 = *(const v4f*)(wb + 384 + fb);
                float i0, i1, i2, i3;
                if (icp) { i0 = r; i1 = th; i2 = ph; i3 = 0.0f; }
                else {
                    float np1 = (set == 0) ? NP0 : ((set == 1) ? 1.0f : NP2);
                    i0 = 0.5f * t * np1; i1 = r; i2 = th; i3 = ph;
                }
                #pragma unroll
                for (int j = 0; j < 4; j++)
                    pre[j] += i0 * w0[j] + i1 * w1[j] + i2 * w2[j] + i3 * w3[j];
                v4f Dk;
                epi_p(pre, Dk, ep0 + (ls * 64) * ROWH);
                v4f t1 = icp ? w0 : w1;
                v4f t2 = icp ? w1 : w2;
                v4f t3 = icp ? w2 : w3;
                epi_t(t1, Dk, ep0 + (ls * 64 + 16) * ROWH);
                epi_t(t2, Dk, ep0 + (ls * 64 + 32) * ROWH);
                epi_t(t3, Dk, ep0 + (ls * 64 + 48) * ROWH);
            }
            __syncthreads();                           // act0 ready

            if (g == 0) {
                hpass(IC<0>{}, IC<0>{}, rd0, ep1); __syncthreads();
                hpass(IC<1>{}, IC<0>{}, rd1, ep0); __syncthreads();
                hpass(IC<2>{}, IC<0>{}, rd0, ep1); __syncthreads();
            } else {
                hpass(IC<0>{}, IC<1>{}, rd0, ep1); __syncthreads();
                hpass(IC<1>{}, IC<1>{}, rd1, ep0); __syncthreads();
                hpass(IC<2>{}, IC<1>{}, rd0, ep1); __syncthreads();
            }

            // out-dot via MFMA: wout fragment loaded transiently from pack
            {
                const bool icout = (g == 1) && (wave >= 4);
                const _Float16* wsf = pack + 106496 + (icout ? 2048 : 0) + (lane << 3);
                v8h wof0 = *(const v8h*)(wsf);
                v8h wof1 = *(const v8h*)(wsf + 512);
                v8h wof2 = *(const v8h*)(wsf + 1024);
                v8h wof3 = *(const v8h*)(wsf + 1536);
                const _Float16* rp = act1 + (wave * 16 + l15) * ROWH + s * 8;
                v4f acc = {0.f, 0.f, 0.f, 0.f};
                acc = __builtin_amdgcn_mfma_f32_16x16x32_f16(wof0, *(const v8h*)(rp),      acc, 0, 0, 0);
                acc = __builtin_amdgcn_mfma_f32_16x16x32_f16(wof1, *(const v8h*)(rp + 32), acc, 0, 0, 0);
                acc = __builtin_amdgcn_mfma_f32_16x16x32_f16(wof2, *(const v8h*)(rp + 64), acc, 0, 0, 0);
                acc = __builtin_amdgcn_mfma_f32_16x16x32_f16(wof3, *(const v8h*)(rp + 96), acc, 0, 0, 0);
                if (s == 0) cbuf[g * 128 + wave * 16 + l15] = acc[0];
            }
        }
        __syncthreads();                               // cbuf complete

        // ---- quadrature + envelope + chain rule (wave 0, lanes 0-15) ----
        if (wave == 0 && lane < 16) {
            int row = b * 16 + lane;
            if (row < N) {
                const float* rbp = rowb + par * 256 + lane * 16;
                float ah = 0.5f * rbp[0];
                float vic = cbuf[192 + lane];
                float g1  = cbuf[208 + lane];
                float g2  = cbuf[224 + lane];
                float g3  = cbuf[240 + lane];
                float dsum = 0.f, ds1 = 0.f, ds2 = 0.f, ds3 = 0.f;
                const float wq[3] = {0.5555555555555556f, 0.8888888888888889f, 0.5555555555555556f};
                #pragma unroll
                for (int qq = 0; qq < 3; qq++) {
                    float w = wq[qq];
                    dsum += w * cbuf[qq * 64 + lane];
                    ds1  += w * cbuf[qq * 64 + 16 + lane];
                    ds2  += w * cbuf[qq * 64 + 32 + lane];
                    ds3  += w * cbuf[qq * 64 + 48 + lane];
                }
                float tcv  = (vic + bouti) + ah * (dsum + 2.0f * boutd);
                float dtcr = g1 + ah * ds1;
                float dtct = g2 + ah * ds2;
                float dtcp = g3 + ah * ds3;
                float sEnv = rbp[9], dsdr = rbp[10], Aan = rbp[11], dAdr = rbp[12];
                float pot = tcv * sEnv + Aan;
                float gx0 = sEnv * dtcr + tcv * dsdr + dAdr;
                float gx1 = sEnv * dtct;
                float gx2 = sEnv * dtcp;
                float ax = -(gx0 * rbp[1] + gx1 * rbp[4] + gx2 * rbp[7]);
                float ay = -(gx0 * rbp[2] + gx1 * rbp[5] + gx2 * rbp[8]);
                float az = -(gx0 * rbp[3] + gx1 * rbp[6]);
                outPot[row] = pot;
                outAcc[row * 3 + 0] = ax;
                outAcc[row * 3 + 1] = ay;
                outAcc[row * 3 + 2] = az;
            }
        }
    }
}

extern "C" void kernel_launch(void* const* d_in, const int* in_sizes, int n_in,
                              void* d_out, int out_size, void* d_ws, size_t ws_size,
                              hipStream_t stream) {
    (void)n_in; (void)out_size;
    const float* tx     = (const float*)d_in[0];
    const float* dpWin  = (const float*)d_in[1];
    const float* dpBin  = (const float*)d_in[2];
    const float* dpWh   = (const float*)d_in[3];
    const float* dpBh   = (const float*)d_in[4];
    const float* dpWout = (const float*)d_in[5];
    const float* dpBout = (const float*)d_in[6];
    const float* icWin  = (const float*)d_in[7];
    const float* icBin  = (const float*)d_in[8];
    const float* icWh   = (const float*)d_in[9];
    const float* icBh   = (const float*)d_in[10];
    const float* icWout = (const float*)d_in[11];
    const float* icBout = (const float*)d_in[12];

    int N = in_sizes[0] / 4;
    if (ws_size < (size_t)(110592 * sizeof(_Float16))) return;
    _Float16* pack = (_Float16*)d_ws;
    float* outPot = (float*)d_out;
    float* outAcc = outPot + N;

    pack_weights<<<(110592 + 255) / 256, 256, 0, stream>>>(dpWh, icWh, dpWin, icWin,
                                                           dpWout, icWout, pack);

    (void)hipFuncSetAttribute(reinterpret_cast<const void*>(node_main),
                              hipFuncAttributeMaxDynamicSharedMemorySize, SMEM_BYTES);
    node_main<<<512, 512, SMEM_BYTES, stream>>>(tx,
        dpBin, dpBh, icBin, icBh, dpWin, icWin, dpBout, icBout,
        pack, outPot, outAcc, N);
}

// Round 13
// 400.715 us; speedup vs baseline: 1.1535x; 1.1535x over previous
//
#include <hip/hip_runtime.h>

typedef _Float16 v8h __attribute__((ext_vector_type(8)));
typedef _Float16 v4h __attribute__((ext_vector_type(4)));
typedef float    v4f __attribute__((ext_vector_type(4)));

template<int V> struct IC { static constexpr int value = V; };

__device__ __forceinline__ float fast_tanh(float x) {
    float e = __expf(2.0f * x);
    return 1.0f - 2.0f / (e + 1.0f);
}

// ---------------------------------------------------------------------------
// pack layout (halves):
//  hidden: idx = ((((pipe*3+l)*8 + nt)*4 + kk)*64 + lane)*8 + j     [0, 98304)
//  L0 (legacy, unused):                                             [98304, 106496)
//  wout A-fragments: 106496 + ((pipe*4 + kk)*64 + lane)*8 + j       [106496, 110592)
// ---------------------------------------------------------------------------
__global__ void pack_weights(const float* __restrict__ dpWh,
                             const float* __restrict__ icWh,
                             const float* __restrict__ dpWin,
                             const float* __restrict__ icWin,
                             const float* __restrict__ dpWout,
                             const float* __restrict__ icWout,
                             _Float16* __restrict__ out) {
    int idx = blockIdx.x * 256 + threadIdx.x;
    if (idx < 98304) {
        int j    = idx & 7;
        int lane = (idx >> 3) & 63;
        int kk   = (idx >> 9) & 3;
        int nt   = (idx >> 11) & 7;
        int lp   = idx >> 14;           // 0..5
        int l    = lp % 3;
        const float* src = (lp >= 3) ? icWh : dpWh;
        int k = kk * 32 + (lane >> 4) * 8 + j;
        int n = nt * 16 + (lane & 15);
        out[idx] = (_Float16)src[(l * 128 + k) * 128 + n];
    } else if (idx < 106496) {
        int f    = idx - 98304;
        int j    = f & 7;
        int lane = (f >> 3) & 63;
        int nt   = (f >> 9) & 7;
        int pipe = (f >> 12) & 1;
        int k = (lane >> 4) * 8 + j;
        int n = nt * 16 + (lane & 15);
        float v = 0.0f;
        if (pipe == 0) { if (k < 4) v = dpWin[k * 128 + n]; }
        else           { if (k < 3) v = icWin[k * 128 + n]; }
        out[idx] = (_Float16)v;
    } else if (idx < 110592) {
        int f    = idx - 106496;
        int j    = f & 7;
        int lane = (f >> 3) & 63;
        int kk   = (f >> 9) & 3;
        int pipe = (f >> 11) & 1;
        float v = 0.0f;
        if ((lane & 15) == 0)
            v = (pipe ? icWout : dpWout)[kk * 32 + (lane >> 4) * 8 + j];
        out[idx] = (_Float16)v;
    }
}

// LDS (dynamic, 151552 B -> 1 block/CU, 8 waves = 2/SIMD):
//   [0,     69632)  act0 : 256 vrows x ROWH halves (vrow = set*64 + st*16 + phys)
//   [69632,139264)  act1
//   [139264,143360) btab : f32[8][128]  0=dpBin 1..3=dpBh 4=icBin 5..7=icBh
//   [143360,147456) winb : f32[8][128]  0..3=dpWin k, 4..6=icWin k, 7=0
//   [147456,148480) woutb: f32[2][128]
//   [148480,149504) cbuf : f32[256]
//   [149504,151552) rowb : f32[2][16][16] geometry, ping-pong by batch parity
#define ROWH 136
#define ABUFH (256 * ROWH)
#define SMEM_BYTES 151552

// Locked at 2 waves/SIMD (512-thread block; 4/SIMD infeasible: r9/r11/r12
// spills). Budget 256 regs/wave -> keep all weights + wout resident, spend
// headroom on ILP (16-tile hpass), and cut VALU per element instead.
__launch_bounds__(512, 2)
__global__ void node_main(const float* __restrict__ tx,
                          const float* __restrict__ dpBin, const float* __restrict__ dpBh,
                          const float* __restrict__ icBin, const float* __restrict__ icBh,
                          const float* __restrict__ dpWin, const float* __restrict__ icWin,
                          const float* __restrict__ dpBout, const float* __restrict__ icBout,
                          const _Float16* __restrict__ pack,
                          float* __restrict__ outPot, float* __restrict__ outAcc,
                          int N)
{
    extern __shared__ char smem[];
    _Float16* act0 = (_Float16*)smem;
    _Float16* act1 = act0 + ABUFH;
    float* btab  = (float*)(smem + 139264);
    float* winb  = (float*)(smem + 143360);
    float* woutb = (float*)(smem + 147456);
    float* cbuf  = (float*)(smem + 148480);
    float* rowb  = (float*)(smem + 149504);

    const int tid  = threadIdx.x;
    const int wave = tid >> 6;          // 0..7 = my 16-feature slice cs
    const int lane = tid & 63;
    const int l15  = lane & 15;
    const int s    = lane >> 4;
    const int cs   = wave;
    const int fb   = cs * 16 + s * 4;   // my 4 output features

    // ---- stage tables ----
    if (tid < 128) {
        woutb[tid]       = dpBout ? 0.0f : 0.0f;  // placeholder overwritten below
    }
    if (tid < 128) {
        woutb[tid] = 0.0f;  // cleared; real fill below
    }
    for (int i = tid; i < 1024; i += 512) {
        int row = i >> 7, col = i & 127;
        float bv, wv;
        if      (row == 0) bv = dpBin[col];
        else if (row <  4) bv = dpBh[(row - 1) * 128 + col];
        else if (row == 4) bv = icBin[col];
        else               bv = icBh[(row - 5) * 128 + col];
        if      (row <  4) wv = dpWin[row * 128 + col];
        else if (row <  7) wv = icWin[(row - 4) * 128 + col];
        else               wv = 0.0f;
        btab[i] = bv;
        winb[i] = wv;
    }

    // ---- persistent weights: all 6 hidden layers (96 regs) ----
    v8h wreg[6][4];
    #pragma unroll
    for (int L = 0; L < 6; L++)
        #pragma unroll
        for (int kk = 0; kk < 4; kk++)
            wreg[L][kk] = *(const v8h*)(pack + (((L * 8 + cs) * 4 + kk) << 9) + (lane << 3));

    // persistent wout A-fragments (16 regs), straight from pack
    v8h wof[4];
    {
        const _Float16* wsf = pack + 106496 + ((wave >= 6) ? 2048 : 0) + (lane << 3);
        #pragma unroll
        for (int kk = 0; kk < 4; kk++)
            wof[kk] = *(const v8h*)(wsf + (kk << 9));
    }

    const float boutd = dpBout[0];
    const float bouti = icBout[0];
    __syncthreads();

    // ---- static LDS bases ----
    _Float16* ep0 = act0 + l15 * ROWH + fb;            // epilogue writes
    _Float16* ep1 = act1 + l15 * ROWH + fb;
    const _Float16* rd0 = act0 + l15 * ROWH + s * 8;   // B-fragment reads
    const _Float16* rd1 = act1 + l15 * ROWH + s * 8;

    // epilogue: lane holds 4 consecutive features of ONE virtual row.
    // Dkh kept packed f16 so tangent scaling is 2x v_pk_mul_f16.
    auto epi_p = [&](v4f acc, v4h& Dkh, _Float16* p) {
        float h0 = fast_tanh(acc[0]), h1 = fast_tanh(acc[1]);
        float h2 = fast_tanh(acc[2]), h3 = fast_tanh(acc[3]);
        Dkh[0] = (_Float16)(1.0f - h0 * h0);
        Dkh[1] = (_Float16)(1.0f - h1 * h1);
        Dkh[2] = (_Float16)(1.0f - h2 * h2);
        Dkh[3] = (_Float16)(1.0f - h3 * h3);
        v4h w = {(_Float16)h0, (_Float16)h1, (_Float16)h2, (_Float16)h3};
        *(v4h*)p = w;
    };
    auto epi_t = [&](v4f acc, const v4h& Dkh, _Float16* p) {
        v4h av = {(_Float16)acc[0], (_Float16)acc[1],
                  (_Float16)acc[2], (_Float16)acc[3]};
        v4h w = av * Dkh;                               // pk_mul
        *(v4h*)p = w;
    };

    // one hidden layer, full batch: 16 stream-uniform tiles
    auto hpass = [&](auto Lc, const _Float16* rb, _Float16* wb) {
        constexpr int L = decltype(Lc)::value;
        #pragma unroll
        for (int set = 0; set < 4; set++) {
            const bool icp = (set == 3);
            const v8h* W = icp ? wreg[L + 3] : wreg[L];
            const float* brow = btab + (icp ? (5 + L) : (1 + L)) * 128 + fb;
            v4h Dkh;
            #pragma unroll
            for (int st = 0; st < 4; st++) {
                const int ro = (set * 64 + st * 16) * ROWH;
                v8h b0 = *(const v8h*)(rb + ro);
                v8h b1 = *(const v8h*)(rb + ro + 32);
                v8h b2 = *(const v8h*)(rb + ro + 64);
                v8h b3 = *(const v8h*)(rb + ro + 96);
                v4f acc;
                if (st == 0) acc = *(const v4f*)brow;
                else { v4f z = {0.f, 0.f, 0.f, 0.f}; acc = z; }
                acc = __builtin_amdgcn_mfma_f32_16x16x32_f16(W[0], b0, acc, 0, 0, 0);
                acc = __builtin_amdgcn_mfma_f32_16x16x32_f16(W[1], b1, acc, 0, 0, 0);
                acc = __builtin_amdgcn_mfma_f32_16x16x32_f16(W[2], b2, acc, 0, 0, 0);
                acc = __builtin_amdgcn_mfma_f32_16x16x32_f16(W[3], b3, acc, 0, 0, 0);
                _Float16* p = wb + (set * 64 + st * 16) * ROWH;
                if (st == 0) epi_p(acc, Dkh, p);
                else         epi_t(acc, Dkh, p);
            }
        }
    };

    const float NP0 = 1.0f - 0.7745966692414834f;   // GL node+1
    const float NP2 = 1.0f + 0.7745966692414834f;

    const int nbat = (N + 15) >> 4;
    int par = 0;
    for (int b = blockIdx.x; b < nbat; b += gridDim.x, par ^= 1) {
        // ---- geometry: wave 0 computes, everyone reads (rowb ping-pong) ----
        if (wave == 0 && lane < 16) {
            int prow = b * 16 + lane;
            float4 q = (prow < N) ? ((const float4*)tx)[prow] : make_float4(0.f, 1.f, 1.f, 1.f);
            float t = q.x, x = q.y, y = q.z, z = q.w;
            float r2 = x * x + y * y + z * z;
            float r  = sqrtf(r2 + 1e-12f);
            float rinv = 1.0f / r;
            float uc = fminf(1.0f, fmaxf(-1.0f, z * rinv));
            float th = acosf(uc);
            float ph = atan2f(y, x);
            float rinv3 = rinv * rinv * rinv;
            float dacos = -1.0f / sqrtf(fmaxf(1.0f - uc * uc, 1e-30f));
            float rho2 = fmaxf(x * x + y * y, 1e-30f);
            float opr  = 1.0f + r;
            float den  = r * r + 0.1f;
            float isq  = 1.0f / sqrtf(den);
            float* rbp = rowb + par * 256 + lane * 16;
            rbp[0]  = t;
            rbp[1]  = x * rinv; rbp[2] = y * rinv; rbp[3] = z * rinv;
            rbp[4]  = dacos * (-x * z * rinv3);
            rbp[5]  = dacos * (-y * z * rinv3);
            rbp[6]  = dacos * (rinv - z * z * rinv3);
            rbp[7]  = -y / rho2;
            rbp[8]  =  x / rho2;
            rbp[9]  = -1.0f / opr;
            rbp[10] =  1.0f / (opr * opr);
            rbp[11] = -isq;
            rbp[12] = r * isq * isq * isq;
            rbp[13] = r; rbp[14] = th; rbp[15] = ph;
        }
        __syncthreads();                               // rowb ready

        const float* rbl = rowb + par * 256 + l15 * 16;
        float t = rbl[0], r = rbl[13], th = rbl[14], ph = rbl[15];

        // ---- L0 (pure fp32 VALU): 4 sets -> act0 ----
        #pragma unroll
        for (int set = 0; set < 4; set++) {
            const bool icp = (set == 3);
            const float* wb = winb + (icp ? 512 : 0);
            v4f pre = *(const v4f*)(btab + (icp ? 512 : 0) + fb);
            v4f w0 = *(const v4f*)(wb + fb);
            v4f w1 = *(const v4f*)(wb + 128 + fb);
            v4f w2 = *(const v4f*)(wb + 256 + fb);
            v4f w3;
            if (icp) { v4f z = {0.f, 0.f, 0.f, 0.f}; w3 = z; }
            else     w3 = *(const v4f*)(wb + 384 + fb);
            float i0, i1, i2, i3;
            if (icp) { i0 = r; i1 = th; i2 = ph; i3 = 0.0f; }
            else {
                float np1 = (set == 0) ? NP0 : ((set == 1) ? 1.0f : NP2);
                i0 = 0.5f * t * np1; i1 = r; i2 = th; i3 = ph;
            }
            #pragma unroll
            for (int j = 0; j < 4; j++)
                pre[j] += i0 * w0[j] + i1 * w1[j] + i2 * w2[j] + i3 * w3[j];
            v4h Dkh;
            epi_p(pre, Dkh, ep0 + (set * 64) * ROWH);
            v4f t1 = icp ? w0 : w1;
            v4f t2 = icp ? w1 : w2;
            v4f t3 = icp ? w2 : w3;
            epi_t(t1, Dkh, ep0 + (set * 64 + 16) * ROWH);
            epi_t(t2, Dkh, ep0 + (set * 64 + 32) * ROWH);
            epi_t(t3, Dkh, ep0 + (set * 64 + 48) * ROWH);
        }
        __syncthreads();                               // act0 ready

        hpass(IC<0>{}, rd0, ep1); __syncthreads();     // h1: act0 -> act1
        hpass(IC<1>{}, rd1, ep0); __syncthreads();     // h2: act1 -> act0
        hpass(IC<2>{}, rd0, ep1); __syncthreads();     // h3: act0 -> act1

        // ---- output dot via MFMA: 2 tiles per wave ----
        #pragma unroll
        for (int tt = 0; tt < 2; tt++) {
            int tname = wave * 2 + tt;
            const _Float16* rp = act1 + (tname * 16 + l15) * ROWH + s * 8;
            v4f acc = {0.f, 0.f, 0.f, 0.f};
            acc = __builtin_amdgcn_mfma_f32_16x16x32_f16(wof[0], *(const v8h*)(rp),      acc, 0, 0, 0);
            acc = __builtin_amdgcn_mfma_f32_16x16x32_f16(wof[1], *(const v8h*)(rp + 32), acc, 0, 0, 0);
            acc = __builtin_amdgcn_mfma_f32_16x16x32_f16(wof[2], *(const v8h*)(rp + 64), acc, 0, 0, 0);
            acc = __builtin_amdgcn_mfma_f32_16x16x32_f16(wof[3], *(const v8h*)(rp + 96), acc, 0, 0, 0);
            if (s == 0) cbuf[tname * 16 + l15] = acc[0];
        }
        __syncthreads();                               // cbuf ready

        // ---- quadrature + envelope + chain rule (wave 0, lanes 0-15) ----
        if (wave == 0 && lane < 16) {
            int row = b * 16 + lane;
            if (row < N) {
                const float* rbp = rowb + par * 256 + lane * 16;
                float ah = 0.5f * rbp[0];
                float vic = cbuf[192 + lane];
                float g1  = cbuf[208 + lane];
                float g2  = cbuf[224 + lane];
                float g3  = cbuf[240 + lane];
                float dsum = 0.f, ds1 = 0.f, ds2 = 0.f, ds3 = 0.f;
                const float wq[3] = {0.5555555555555556f, 0.8888888888888889f, 0.5555555555555556f};
                #pragma unroll
                for (int qq = 0; qq < 3; qq++) {
                    float w = wq[qq];
                    dsum += w * cbuf[qq * 64 + lane];
                    ds1  += w * cbuf[qq * 64 + 16 + lane];
                    ds2  += w * cbuf[qq * 64 + 32 + lane];
                    ds3  += w * cbuf[qq * 64 + 48 + lane];
                }
                float tcv  = (vic + bouti) + ah * (dsum + 2.0f * boutd);
                float dtcr = g1 + ah * ds1;
                float dtct = g2 + ah * ds2;
                float dtcp = g3 + ah * ds3;
                float sEnv = rbp[9], dsdr = rbp[10], Aan = rbp[11], dAdr = rbp[12];
                float pot = tcv * sEnv + Aan;
                float gx0 = sEnv * dtcr + tcv * dsdr + dAdr;
                float gx1 = sEnv * dtct;
                float gx2 = sEnv * dtcp;
                float ax = -(gx0 * rbp[1] + gx1 * rbp[4] + gx2 * rbp[7]);
                float ay = -(gx0 * rbp[2] + gx1 * rbp[5] + gx2 * rbp[8]);
                float az = -(gx0 * rbp[3] + gx1 * rbp[6]);
                outPot[row] = pot;
                outAcc[row * 3 + 0] = ax;
                outAcc[row * 3 + 1] = ay;
                outAcc[row * 3 + 2] = az;
            }
        }
    }
}

extern "C" void kernel_launch(void* const* d_in, const int* in_sizes, int n_in,
                              void* d_out, int out_size, void* d_ws, size_t ws_size,
                              hipStream_t stream) {
    (void)n_in; (void)out_size;
    const float* tx     = (const float*)d_in[0];
    const float* dpWin  = (const float*)d_in[1];
    const float* dpBin  = (const float*)d_in[2];
    const float* dpWh   = (const float*)d_in[3];
    const float* dpBh   = (const float*)d_in[4];
    const float* dpWout = (const float*)d_in[5];
    const float* dpBout = (const float*)d_in[6];
    const float* icWin  = (const float*)d_in[7];
    const float* icBin  = (const float*)d_in[8];
    const float* icWh   = (const float*)d_in[9];
    const float* icBh   = (const float*)d_in[10];
    const float* icWout = (const float*)d_in[11];
    const float* icBout = (const float*)d_in[12];

    int N = in_sizes[0] / 4;
    if (ws_size < (size_t)(110592 * sizeof(_Float16))) return;
    _Float16* pack = (_Float16*)d_ws;
    float* outPot = (float*)d_out;
    float* outAcc = outPot + N;

    pack_weights<<<(110592 + 255) / 256, 256, 0, stream>>>(dpWh, icWh, dpWin, icWin,
                                                           dpWout, icWout, pack);

    (void)hipFuncSetAttribute(reinterpret_cast<const void*>(node_main),
                              hipFuncAttributeMaxDynamicSharedMemorySize, SMEM_BYTES);
    node_main<<<256, 512, SMEM_BYTES, stream>>>(tx,
        dpBin, dpBh, icBin, icBh, dpWin, icWin, dpBout, icBout,
        pack, outPot, outAcc, N);
}